// Round 1
// baseline (1444.276 us; speedup 1.0000x reference)
//
#include <hip/hip_runtime.h>
#include <stdint.h>

// 1 = partitionable threefry (JAX >= 0.4.36 default): bits = y0 ^ y1 of TF((0,42),(0,i))
// 0 = original/legacy scheme: concat of halves
#ifndef GUMBEL_SCHEME
#define GUMBEL_SCHEME 1
#endif

constexpr int B_ = 64;
constexpr int D_ = 4096;
constexpr int V_ = 50257;

// ---------------- Threefry-2x32-20, key = (0, 42) ----------------
__device__ __forceinline__ void tf_round(uint32_t& x0, uint32_t& x1, int r) {
  x0 += x1;
  x1 = (x1 << r) | (x1 >> (32 - r));
  x1 ^= x0;
}

__device__ __forceinline__ void threefry2x32(uint32_t xx0, uint32_t xx1,
                                             uint32_t& y0, uint32_t& y1) {
  const uint32_t k0 = 0u, k1 = 42u;
  const uint32_t k2 = 0x1BD11BDAu ^ k0 ^ k1;
  uint32_t x0 = xx0 + k0, x1 = xx1 + k1;
  tf_round(x0, x1, 13); tf_round(x0, x1, 15); tf_round(x0, x1, 26); tf_round(x0, x1, 6);
  x0 += k1; x1 += k2 + 1u;
  tf_round(x0, x1, 17); tf_round(x0, x1, 29); tf_round(x0, x1, 16); tf_round(x0, x1, 24);
  x0 += k2; x1 += k0 + 2u;
  tf_round(x0, x1, 13); tf_round(x0, x1, 15); tf_round(x0, x1, 26); tf_round(x0, x1, 6);
  x0 += k0; x1 += k1 + 3u;
  tf_round(x0, x1, 17); tf_round(x0, x1, 29); tf_round(x0, x1, 16); tf_round(x0, x1, 24);
  x0 += k1; x1 += k2 + 4u;
  tf_round(x0, x1, 13); tf_round(x0, x1, 15); tf_round(x0, x1, 26); tf_round(x0, x1, 6);
  x0 += k2; x1 += k0 + 5u;
  y0 = x0; y1 = x1;
}

__device__ __forceinline__ uint32_t rand_bits(uint32_t flat_idx) {
  uint32_t y0, y1;
#if GUMBEL_SCHEME
  threefry2x32(0u, flat_idx, y0, y1);
  return y0 ^ y1;
#else
  const uint32_t HALF = (uint32_t)(B_ * (long)V_ / 2);  // 1608224
  uint32_t j = (flat_idx < HALF) ? flat_idx : flat_idx - HALF;
  threefry2x32(j, j + HALF, y0, y1);
  return (flat_idx < HALF) ? y0 : y1;
#endif
}

__device__ __forceinline__ float gumbel_from_bits(uint32_t r) {
  // u = max(tiny, bitcast((r>>9)|0x3f800000) - 1)  (exactly JAX's uniform in fp32)
  float f = __uint_as_float((r >> 9) | 0x3F800000u) - 1.0f;
  float u = fmaxf(1.17549435e-38f, f);
  return -logf(-logf(u));
}

// ---------------- monotone fp32<->uint32 ----------------
__device__ __forceinline__ uint32_t f2mono(float f) {
  uint32_t u = __float_as_uint(f);
  return u ^ (0x80000000u | (uint32_t)((int32_t)u >> 31));
}
__device__ __forceinline__ float mono2f(uint32_t m) {
  uint32_t u = (m & 0x80000000u) ? (m ^ 0x80000000u) : ~m;
  return __uint_as_float(u);
}

// ======================= GEMM: logits = H @ W^T / temp =======================
// 64(batch) x 128(vocab) tile, BK=64, 256 threads, 4x8 per thread.
__global__ __launch_bounds__(256) void gemm_logits(
    const float* __restrict__ H, const float* __restrict__ W,
    const float* __restrict__ T, float* __restrict__ logits) {
  constexpr int TN = 128, BK = 64;
  __shared__ float Ash[64][BK + 4];   // [batch][k], 16B-aligned rows (stride 68)
  __shared__ float Bsh[BK][TN + 4];   // [k][vocab], stride 132

  const int tid = threadIdx.x;
  const int tx = tid & 15;   // vocab group
  const int ty = tid >> 4;   // batch group
  const int n0 = blockIdx.x * TN;

  float acc[4][8];
#pragma unroll
  for (int i = 0; i < 4; i++)
#pragma unroll
    for (int j = 0; j < 8; j++) acc[i][j] = 0.f;

  for (int k0 = 0; k0 < D_; k0 += BK) {
    // stage A: 64 x 64, row-major, vector stores
#pragma unroll
    for (int i = 0; i < 4; i++) {
      const int li = tid + i * 256;
      const int row = li >> 4, c4 = li & 15;
      const float4 v = *(const float4*)(H + (size_t)row * D_ + k0 + (c4 << 2));
      *(float4*)&Ash[row][c4 << 2] = v;
    }
    // stage B: 128 x 64, transposed into [k][vocab]
#pragma unroll
    for (int i = 0; i < 8; i++) {
      const int li = tid + i * 256;
      const int row = li >> 4, c4 = li & 15;
      int gr = n0 + row; gr = (gr < V_) ? gr : (V_ - 1);
      const float4 v = *(const float4*)(W + (size_t)gr * D_ + k0 + (c4 << 2));
      Bsh[(c4 << 2) + 0][row] = v.x;
      Bsh[(c4 << 2) + 1][row] = v.y;
      Bsh[(c4 << 2) + 2][row] = v.z;
      Bsh[(c4 << 2) + 3][row] = v.w;
    }
    __syncthreads();
#pragma unroll
    for (int kk = 0; kk < BK; kk += 4) {
      float4 a[4], b0[4], b1[4];
#pragma unroll
      for (int i2 = 0; i2 < 4; i2++) a[i2] = *(const float4*)&Ash[(ty << 2) + i2][kk];
#pragma unroll
      for (int t = 0; t < 4; t++) {
        b0[t] = *(const float4*)&Bsh[kk + t][tx << 2];
        b1[t] = *(const float4*)&Bsh[kk + t][64 + (tx << 2)];
      }
#pragma unroll
      for (int i2 = 0; i2 < 4; i2++) {
#pragma unroll
        for (int t = 0; t < 4; t++) {
          const float av = ((const float*)&a[i2])[t];
          const float* bp0 = (const float*)&b0[t];
          const float* bp1 = (const float*)&b1[t];
#pragma unroll
          for (int j = 0; j < 4; j++) {
            acc[i2][j]     = fmaf(av, bp0[j], acc[i2][j]);
            acc[i2][j + 4] = fmaf(av, bp1[j], acc[i2][j + 4]);
          }
        }
      }
    }
    __syncthreads();
  }

#pragma unroll
  for (int i2 = 0; i2 < 4; i2++) {
    const int mrow = (ty << 2) + i2;
    const float tmp = T[mrow];
#pragma unroll
    for (int j = 0; j < 8; j++) {
      const int n = n0 + ((j < 4) ? ((tx << 2) + j) : (64 + (tx << 2) + (j - 4)));
      if (n < V_) logits[(size_t)mrow * V_ + n] = acc[i2][j] / tmp;  // IEEE div
    }
  }
}

// ======================= fused top-p mask + gumbel argmax =======================
constexpr int TPB = 1024;
constexpr int NPER = (V_ + TPB - 1) / TPB;  // 50
static_assert(NPER * TPB >= V_, "coverage");

__device__ float blk_reduce_sum(float v, volatile float* red, float* bc) {
  const int tid = threadIdx.x;
#pragma unroll
  for (int off = 32; off > 0; off >>= 1) v += __shfl_down(v, off);
  if ((tid & 63) == 0) red[tid >> 6] = v;
  __syncthreads();
  if (tid == 0) {
    float s = 0.f;
#pragma unroll
    for (int w = 0; w < 16; w++) s += red[w];
    *bc = s;
  }
  __syncthreads();
  const float r = *bc;
  __syncthreads();
  return r;
}

__device__ float blk_reduce_max(float v, volatile float* red, float* bc) {
  const int tid = threadIdx.x;
#pragma unroll
  for (int off = 32; off > 0; off >>= 1) v = fmaxf(v, __shfl_down(v, off));
  if ((tid & 63) == 0) red[tid >> 6] = v;
  __syncthreads();
  if (tid == 0) {
    float s = -INFINITY;
#pragma unroll
    for (int w = 0; w < 16; w++) s = fmaxf(s, red[w]);
    *bc = s;
  }
  __syncthreads();
  const float r = *bc;
  __syncthreads();
  return r;
}

__global__ __launch_bounds__(TPB) void topp_sample(
    float* __restrict__ logits, const float* __restrict__ top_p,
    int* __restrict__ out) {
  __shared__ float red[16];
  __shared__ float bcf;
  __shared__ float redv[16];
  __shared__ int redi[16];
  __shared__ int wct[16];
  __shared__ int runbase;

  const int b = blockIdx.x;
  const int tid = threadIdx.x;
  float* __restrict__ L = logits + (size_t)b * V_;

  float l[NPER];
#pragma unroll
  for (int i = 0; i < NPER; i++) {
    const int v = tid + i * TPB;
    l[i] = (v < V_) ? L[v] : -INFINITY;
  }

  // row max
  float m = -INFINITY;
#pragma unroll
  for (int i = 0; i < NPER; i++) m = fmaxf(m, l[i]);
  const float M = blk_reduce_max(m, red, &bcf);

  // Z = sum exp(l - M)   (exp(-inf)=0 handles tail)
  float zl = 0.f;
#pragma unroll
  for (int i = 0; i < NPER; i++) zl += expf(l[i] - M);
  const float Z = blk_reduce_sum(zl, red, &bcf);
  const float P = top_p[b] * Z;   // compare cumsums in exp-numerator space

  // binary search: smallest c with S(c) = sum_{l>c} exp(l-M) <= P
  uint32_t lo = 0x007FFFFFu;      // mono(-inf)
  uint32_t hi = f2mono(M);        // S(M)=0 <= P
  float s_hi = 0.f;
  while (hi - lo > 1u) {
    const uint32_t mid = lo + ((hi - lo) >> 1);
    const float c = mono2f(mid);
    float sl = 0.f;
#pragma unroll
    for (int i = 0; i < NPER; i++) sl += (l[i] > c) ? expf(l[i] - M) : 0.f;
    const float s = blk_reduce_sum(sl, red, &bcf);
    if (s <= P) { hi = mid; s_hi = s; } else { lo = mid; }
  }
  const float cstar = mono2f(hi);

  // ties at cstar: keep first kk in index order (stable sort semantics)
  float ntl = 0.f;
#pragma unroll
  for (int i = 0; i < NPER; i++) ntl += (l[i] == cstar) ? 1.f : 0.f;
  const int n_tie = (int)blk_reduce_sum(ntl, red, &bcf);
  const float p_num = expf(cstar - M);
  int kk = 0;
  {
    float s = s_hi;
    for (int j = 0; j < n_tie; j++) {
      if (s <= P) { kk++; s += p_num; } else break;
    }
  }
  if (kk < n_tie) {
    // mask ties with index-rank >= kk (write -inf to global; same thread re-reads later)
    if (tid == 0) runbase = 0;
    __syncthreads();
    for (int i = 0; i < NPER; i++) {
      const int v = tid + i * TPB;
      const bool tie = (v < V_) && (l[i] == cstar);
      const unsigned long long mk = __ballot(tie);
      const int wid = tid >> 6, lane = tid & 63;
      if (lane == 0) wct[wid] = __popcll(mk);
      __syncthreads();
      int pre = runbase;
      for (int w = 0; w < wid; w++) pre += wct[w];
      if (lane) pre += __popcll(mk & ((~0ull) >> (64 - lane)));
      if (tie && pre >= kk) L[v] = -INFINITY;
      __syncthreads();
      if (tid == 0) {
        int t = 0;
        for (int w = 0; w < 16; w++) t += wct[w];
        runbase += t;
      }
      __syncthreads();
    }
  }

  // gumbel + argmax over kept set (lv >= cstar; masked ties were set to -inf)
  float best = -INFINITY;
  int bidx = 0x7FFFFFFF;
  for (int i = 0; i < NPER; i++) {
    const int v = tid + i * TPB;
    if (v >= V_) break;
    const float lv = L[v];
    const uint32_t gi = (uint32_t)(b * V_ + v);
    const float g = gumbel_from_bits(rand_bits(gi));
    const float val = (lv >= cstar) ? (g + lv) : -INFINITY;
    if (val > best) { best = val; bidx = v; }
  }
#pragma unroll
  for (int off = 32; off > 0; off >>= 1) {
    const float ov = __shfl_down(best, off);
    const int oi = __shfl_down(bidx, off);
    if (ov > best || (ov == best && oi < bidx)) { best = ov; bidx = oi; }
  }
  const int wid = tid >> 6, lane = tid & 63;
  if (lane == 0) { redv[wid] = best; redi[wid] = bidx; }
  __syncthreads();
  if (tid == 0) {
    float bv = redv[0]; int bi = redi[0];
    for (int w = 1; w < 16; w++)
      if (redv[w] > bv || (redv[w] == bv && redi[w] < bi)) { bv = redv[w]; bi = redi[w]; }
    out[b] = bi;
  }
}

// ======================= launch =======================
extern "C" void kernel_launch(void* const* d_in, const int* in_sizes, int n_in,
                              void* d_out, int out_size, void* d_ws, size_t ws_size,
                              hipStream_t stream) {
  const float* H = (const float*)d_in[0];     // [64, 4096]
  const float* W = (const float*)d_in[1];     // [50257, 4096]
  const float* T = (const float*)d_in[2];     // [64]
  const float* topp = (const float*)d_in[3];  // [64]
  float* logits = (float*)d_ws;               // 64*50257 floats = 12.87 MB
  int* out = (int*)d_out;

  const int nblk = (V_ + 127) / 128;          // 393
  gemm_logits<<<dim3(nblk), dim3(256), 0, stream>>>(H, W, T, logits);
  topp_sample<<<dim3(B_), dim3(TPB), 0, stream>>>(logits, topp, out);
}